// Round 6
// baseline (11.483 us; speedup 1.0000x reference)
//
#include <hip/hip_runtime.h>
#include <hip/hip_bf16.h>

#define VOCAB 32000
#define EMBED 128
#define NTOK  (4 * 2048)
#define TV    128           // vocab columns per block -> 512B contiguous read bursts
#define BLK   1024          // 16 waves

// out[t][:] = W[:, e[t]] + bias.
// Per block (owns vocab range [v0, v0+128)):
//   1) each wave prefetches its 512-id slice of e into 2 int4 registers and
//      the lane's 2 bias values into a float2 (in flight alongside staging),
//   2) stages the [128][128] W tile (64 KB) linearly into LDS via async
//      global_load_lds width=16: 64 chunks of 1KB, each covering 2 rows of
//      512B contiguous W data (2x longer bursts than TV=64),
//   3) one barrier (drains vmcnt),
//   4) register ballot scan over this wave's 512 ids; each matched token's
//      512B row is emitted by the whole wave (float2/lane, one coalesced
//      store). ~33 matches/block total -> emit phase is noise.
__global__ __launch_bounds__(BLK) void embed_tile(const int* __restrict__ e,
                                                  const float* __restrict__ W,
                                                  const float* __restrict__ bias,
                                                  float* __restrict__ out) {
    __shared__ float lds[EMBED * TV];   // [d][c] linear, 64 KB

    const int tid  = threadIdx.x;
    const int lane = tid & 63;
    const int wid  = tid >> 6;               // 0..15
    const int v0   = blockIdx.x * TV;

    // (1) e-slice prefetch: wave wid owns ids [wid*512, wid*512+512)
    const int wbase = wid << 9;
    int4 ebuf[2];
    #pragma unroll
    for (int s = 0; s < 2; ++s)
        ebuf[s] = *reinterpret_cast<const int4*>(&e[wbase + (s << 8) + (lane << 2)]);

    const float2 bl = *reinterpret_cast<const float2*>(&bias[lane << 1]);

    // (2) async stage: chunk k covers rows d=2k, 2k+1 (512B each, contiguous).
    //     lane's src: row = 2k + (lane>>5), cols v0 + (lane&31)*4 (16B).
    //     LDS dest = &lds[k*256] + lane*16 (HW), matching [d][c] linear.
    #pragma unroll
    for (int i = 0; i < 4; ++i) {
        const int k = (wid << 2) + i;
        const int d = (k << 1) + (lane >> 5);
        const int c = (lane & 31) << 2;
        __builtin_amdgcn_global_load_lds(
            (const __attribute__((address_space(1))) void*)(&W[d * VOCAB + v0 + c]),
            (__attribute__((address_space(3))) void*)(&lds[k << 8]),
            16, 0, 0);
    }
    __syncthreads();   // tile + ebuf ready

    // (4) ballot scan + cooperative emit
    const int l2 = lane << 1;
    #pragma unroll
    for (int s = 0; s < 2; ++s) {
        const int tok[4] = {ebuf[s].x, ebuf[s].y, ebuf[s].z, ebuf[s].w};
        #pragma unroll
        for (int j = 0; j < 4; ++j) {
            const unsigned c = (unsigned)(tok[j] - v0);
            unsigned long long m = __ballot(c < TV);
            while (m) {
                const int src = __builtin_ctzll(m);
                m &= m - 1;
                const int cc = __shfl((int)c, src, 64);
                const int tt = wbase + (s << 8) + (src << 2) + j;
                float2 v;
                v.x = lds[(l2 + 0) * TV + cc] + bl.x;
                v.y = lds[(l2 + 1) * TV + cc] + bl.y;
                *reinterpret_cast<float2*>(&out[tt * EMBED + l2]) = v;  // 512B/wave
            }
        }
    }
}

extern "C" void kernel_launch(void* const* d_in, const int* in_sizes, int n_in,
                              void* d_out, int out_size, void* d_ws, size_t ws_size,
                              hipStream_t stream) {
    const int*   e    = (const int*)d_in[0];
    const float* W    = (const float*)d_in[1];
    const float* bias = (const float*)d_in[2];
    float*       out  = (float*)d_out;

    const int grid = VOCAB / TV;   // 250 blocks
    embed_tile<<<grid, BLK, 0, stream>>>(e, W, bias, out);
}

// Round 8
// 10.508 us; speedup vs baseline: 1.0928x; 1.0928x over previous
//
#include <hip/hip_runtime.h>
#include <hip/hip_bf16.h>

#define VOCAB 32000
#define EMBED 128
#define NTOK  (4 * 2048)
#define TV    64            // vocab columns per block
#define BLK   256           // 4 waves

// out[t][:] = W[:, e[t]] + bias.
// Per block (owns vocab range [v0, v0+64)):
//   1) stage the [128][64] W tile (32 KB = 32 chunks of 1KB) linearly into
//      LDS via async global_load_lds width=16 — issued FIRST so the cold-HBM
//      W stream heads each wave's vmcnt queue. 4 waves x 8 chunks = 32. (R7
//      bug: 4 waves x 4 chunks staged only half the tile.)
//   2) then prefetch this wave's 2048-id e-slice into 8 int4 registers and
//      the lane's 2 bias values (L2-resident, completes under W latency),
//   3) one barrier (drains vmcnt(0): tile + ebuf ready),
//   4) pure-register ballot scan; each matched token's 512B row is emitted
//      by the whole wave (float2/lane, one coalesced 512B store). ~16
//      matches/block -> emit phase is noise.
__global__ __launch_bounds__(BLK) void embed_tile(const int* __restrict__ e,
                                                  const float* __restrict__ W,
                                                  const float* __restrict__ bias,
                                                  float* __restrict__ out) {
    __shared__ float lds[EMBED * TV];   // [d][c] linear, 32 KB (load_lds needs linear)

    const int tid  = threadIdx.x;
    const int lane = tid & 63;
    const int wid  = tid >> 6;              // 0..3
    const int v0   = blockIdx.x * TV;

    // (1) async stage: chunk k = wid*8+i is 1KB covering rows d=4k..4k+3.
    //     lane src: row d = 4k + (lane>>4), cols v0 + (lane&15)*4 (16B).
    //     HW LDS dest = base + lane*16, matching [d][c] linear layout.
    #pragma unroll
    for (int i = 0; i < 8; ++i) {
        const int k = (wid << 3) + i;        // 0..31 across 4 waves
        const int d = (k << 2) + (lane >> 4);
        const int c = (lane & 15) << 2;
        __builtin_amdgcn_global_load_lds(
            (const __attribute__((address_space(1))) void*)(&W[d * VOCAB + v0 + c]),
            (__attribute__((address_space(3))) void*)(&lds[k << 8]),
            16, 0, 0);
    }

    // (2) e-slice prefetch: wave wid owns ids [wid*2048, wid*2048+2048)
    const int wbase = wid << 11;
    int4 ebuf[8];
    #pragma unroll
    for (int s = 0; s < 8; ++s)
        ebuf[s] = *reinterpret_cast<const int4*>(&e[wbase + (s << 8) + (lane << 2)]);

    const float2 bl = *reinterpret_cast<const float2*>(&bias[lane << 1]);

    __syncthreads();   // vmcnt(0) drained: tile + ebuf ready

    // (4) ballot scan + cooperative emit
    const int l2 = lane << 1;
    #pragma unroll
    for (int s = 0; s < 8; ++s) {
        const int tok[4] = {ebuf[s].x, ebuf[s].y, ebuf[s].z, ebuf[s].w};
        #pragma unroll
        for (int j = 0; j < 4; ++j) {
            const unsigned c = (unsigned)(tok[j] - v0);
            unsigned long long m = __ballot(c < TV);
            while (m) {
                const int src = __builtin_ctzll(m);
                m &= m - 1;
                const int cc = __shfl((int)c, src, 64);
                const int tt = wbase + (s << 8) + (src << 2) + j;
                float2 v;
                v.x = lds[(l2 + 0) * TV + cc] + bl.x;
                v.y = lds[(l2 + 1) * TV + cc] + bl.y;
                *reinterpret_cast<float2*>(&out[tt * EMBED + l2]) = v;  // 512B/wave
            }
        }
    }
}

extern "C" void kernel_launch(void* const* d_in, const int* in_sizes, int n_in,
                              void* d_out, int out_size, void* d_ws, size_t ws_size,
                              hipStream_t stream) {
    const int*   e    = (const int*)d_in[0];
    const float* W    = (const float*)d_in[1];
    const float* bias = (const float*)d_in[2];
    float*       out  = (float*)d_out;

    const int grid = VOCAB / TV;   // 500 blocks
    embed_tile<<<grid, BLK, 0, stream>>>(e, W, bias, out);
}

// Round 9
// 10.030 us; speedup vs baseline: 1.1448x; 1.0477x over previous
//
#include <hip/hip_runtime.h>
#include <hip/hip_bf16.h>

#define VOCAB 32000
#define EMBED 128
#define NTOK  (4 * 2048)
#define TV    64            // vocab columns per block
#define BLK   512           // 8 waves

typedef float f32x2 __attribute__((ext_vector_type(2)));

// out[t][:] = W[:, e[t]] + bias.
// Per block (owns vocab range [v0, v0+64)):
//   1) each wave prefetches its 1024-id e-slice into 4 int4 registers and the
//      lane's 2 bias values (normal cached loads — e/bias are re-read by all
//      500 blocks and should stay L2-resident),
//   2) stages the [128][64] W tile (32 KB) linearly into LDS via async
//      global_load_lds width=16 with aux=NT (non-allocating): W is one-shot
//      per replay and the harness's 268MB poison fill evicts it anyway, so
//      allocating it in L2/L3 only forces demand writebacks of dirty poison
//      lines that halve effective HBM read BW,
//   3) one barrier (drains vmcnt(0)),
//   4) pure-register ballot scan; each matched token's 512B row is emitted by
//      the whole wave via NONTEMPORAL float2 stores (no-allocate: out is not
//      re-read in-kernel; avoids more poison-line evictions).
__global__ __launch_bounds__(BLK) void embed_tile(const int* __restrict__ e,
                                                  const float* __restrict__ W,
                                                  const float* __restrict__ bias,
                                                  float* __restrict__ out) {
    __shared__ float lds[EMBED * TV];   // [d][c] linear, 32 KB (load_lds needs linear)

    const int tid  = threadIdx.x;
    const int lane = tid & 63;
    const int wid  = tid >> 6;              // 0..7
    const int v0   = blockIdx.x * TV;

    // (1) e-slice prefetch: wave wid owns ids [wid*1024, wid*1024+1024)
    const int wbase = wid << 10;
    int4 ebuf[4];
    #pragma unroll
    for (int s = 0; s < 4; ++s)
        ebuf[s] = *reinterpret_cast<const int4*>(&e[wbase + (s << 8) + (lane << 2)]);

    const float2 bl = *reinterpret_cast<const float2*>(&bias[lane << 1]);

    // (2) async NT stage: chunk k = wid*4+i is 1KB covering rows d=4k..4k+3.
    //     lane src: row d = 4k + (lane>>4), cols v0 + (lane&15)*4 (16B).
    //     HW LDS dest = base + lane*16, matching [d][c] linear layout.
    #pragma unroll
    for (int i = 0; i < 4; ++i) {
        const int k = (wid << 2) + i;        // 0..31
        const int d = (k << 2) + (lane >> 4);
        const int c = (lane & 15) << 2;
        __builtin_amdgcn_global_load_lds(
            (const __attribute__((address_space(1))) void*)(&W[d * VOCAB + v0 + c]),
            (__attribute__((address_space(3))) void*)(&lds[k << 8]),
            16, 0, /*aux=NT*/ 2);
    }
    __syncthreads();   // vmcnt(0) drained: tile + ebuf ready

    // (4) ballot scan + cooperative emit (nontemporal stores)
    const int l2 = lane << 1;
    #pragma unroll
    for (int s = 0; s < 4; ++s) {
        const int tok[4] = {ebuf[s].x, ebuf[s].y, ebuf[s].z, ebuf[s].w};
        #pragma unroll
        for (int j = 0; j < 4; ++j) {
            const unsigned c = (unsigned)(tok[j] - v0);
            unsigned long long m = __ballot(c < TV);
            while (m) {
                const int src = __builtin_ctzll(m);
                m &= m - 1;
                const int cc = __shfl((int)c, src, 64);
                const int tt = wbase + (s << 8) + (src << 2) + j;
                f32x2 v;
                v.x = lds[(l2 + 0) * TV + cc] + bl.x;
                v.y = lds[(l2 + 1) * TV + cc] + bl.y;
                __builtin_nontemporal_store(
                    v, reinterpret_cast<f32x2*>(&out[tt * EMBED + l2]));  // 512B/wave
            }
        }
    }
}

extern "C" void kernel_launch(void* const* d_in, const int* in_sizes, int n_in,
                              void* d_out, int out_size, void* d_ws, size_t ws_size,
                              hipStream_t stream) {
    const int*   e    = (const int*)d_in[0];
    const float* W    = (const float*)d_in[1];
    const float* bias = (const float*)d_in[2];
    float*       out  = (float*)d_out;

    const int grid = VOCAB / TV;   // 500 blocks
    embed_tile<<<grid, BLK, 0, stream>>>(e, W, bias, out);
}